// Round 1
// baseline (413.625 us; speedup 1.0000x reference)
//
#include <hip/hip_runtime.h>

typedef short short8 __attribute__((ext_vector_type(8)));
typedef short short4v __attribute__((ext_vector_type(4)));
typedef float f32x4 __attribute__((ext_vector_type(4)));
typedef __bf16 bf16x8 __attribute__((ext_vector_type(8)));

__device__ __forceinline__ short f2bf(float x) {
  unsigned u = __builtin_bit_cast(unsigned, x);
  u += 0x7fffu + ((u >> 16) & 1u);   // round-to-nearest-even
  return (short)(u >> 16);
}

__device__ __forceinline__ f32x4 mfma16(short8 a, short8 b, f32x4 c) {
  return __builtin_amdgcn_mfma_f32_16x16x32_bf16(
      __builtin_bit_cast(bf16x8, a), __builtin_bit_cast(bf16x8, b), c, 0, 0, 0);
}

// ---------------- conversion kernels ----------------

__global__ __launch_bounds__(256) void cvt_bf16_kernel(
    const float* __restrict__ x, short* __restrict__ y, int n) {
  int i = blockIdx.x * 256 + threadIdx.x;
  if (i < n) y[i] = f2bf(x[i]);
}

// W: [K][N] f32 row-major  ->  BT: [N][K] bf16 row-major
__global__ __launch_bounds__(256) void transpose_cvt_kernel(
    const float* __restrict__ W, short* __restrict__ BT, int K, int N) {
  __shared__ short tile[32][33];
  int bn = blockIdx.x * 32, bk = blockIdx.y * 32;
  int tx = threadIdx.x, ty = threadIdx.y;  // 32 x 8
  for (int i = ty; i < 32; i += 8)
    tile[i][tx] = f2bf(W[(size_t)(bk + i) * N + bn + tx]);
  __syncthreads();
  for (int i = ty; i < 32; i += 8)
    BT[(size_t)(bn + i) * K + bk + tx] = tile[tx][i];
}

// ---------------- GEMM: C[M,N] = A[M,K] @ BT[N,K]^T ----------------
// A,BT bf16 row-major. EPI=0: store f32 C. EPI=1: out = acc + bias[col] + resid.

template <int EPI>
__global__ __launch_bounds__(256) void gemm_bt_kernel(
    const short* __restrict__ A, const short* __restrict__ BT,
    int M, int N, int K, float* __restrict__ C,
    const float* __restrict__ bias, const float* __restrict__ resid,
    float* __restrict__ out) {
  int tid = threadIdx.x;
  int l = tid & 63, w = tid >> 6;
  int wr = w >> 1, wc = w & 1;
  int lr = l & 15, lg = l >> 4;
  int bm = blockIdx.y * 64, bn = blockIdx.x * 64;
  f32x4 acc[2][2] = {};
  const short* arow = A + (size_t)(bm + wr * 32 + lr) * K + lg * 8;
  const short* brow = BT + (size_t)(bn + wc * 32 + lr) * K + lg * 8;
  for (int k0 = 0; k0 < K; k0 += 32) {
    short8 a0 = *(const short8*)(arow + k0);
    short8 a1 = *(const short8*)(arow + (size_t)16 * K + k0);
    short8 b0 = *(const short8*)(brow + k0);
    short8 b1 = *(const short8*)(brow + (size_t)16 * K + k0);
    acc[0][0] = mfma16(a0, b0, acc[0][0]);
    acc[0][1] = mfma16(a0, b1, acc[0][1]);
    acc[1][0] = mfma16(a1, b0, acc[1][0]);
    acc[1][1] = mfma16(a1, b1, acc[1][1]);
  }
#pragma unroll
  for (int mi = 0; mi < 2; mi++)
#pragma unroll
    for (int ni = 0; ni < 2; ni++)
#pragma unroll
      for (int i = 0; i < 4; i++) {
        int row = bm + wr * 32 + mi * 16 + lg * 4 + i;
        int col = bn + wc * 32 + ni * 16 + lr;
        float v = acc[mi][ni][i];
        if (EPI == 1)
          out[(size_t)row * N + col] = v + bias[col] + resid[(size_t)row * N + col];
        else
          C[(size_t)row * N + col] = v;
      }
}

// ---------------- CAPE + head split ----------------
// qkv: [2048][3840] f32 (cols 0-1279 q, 1280-2559 k, 2560-3839 v)
// qb,kb: [20][2048][64] bf16 ; vt: [20][64][2048] bf16
__global__ __launch_bounds__(256) void cape_split_kernel(
    const float* __restrict__ qkv, const float* __restrict__ p_out,
    const float* __restrict__ p_inv, short* __restrict__ qb,
    short* __restrict__ kb, short* __restrict__ vt) {
  int idx = blockIdx.x * 256 + threadIdx.x;  // s*320 + g, grid is exact
  int s = idx / 320;
  int g = idx - s * 320;
  int t = s >> 10;
  const float* Pq = p_inv + t * 16;   // q uses p_out_inv
  const float* Pk = p_out + t * 16;   // k uses p_out
  const float* row = qkv + (size_t)s * 3840 + g * 4;
  float qv[4], kv[4], vv[4];
#pragma unroll
  for (int i = 0; i < 4; i++) {
    qv[i] = row[i];
    kv[i] = row[1280 + i];
    vv[i] = row[2560 + i];
  }
  int h = g >> 4;
  int dvb = (g & 15) * 4;
  short4v qo, ko;
#pragma unroll
  for (int j = 0; j < 4; j++) {
    float aq = 0.f, ak = 0.f;
#pragma unroll
    for (int k2 = 0; k2 < 4; k2++) {
      aq += qv[k2] * Pq[k2 * 4 + j];
      ak += kv[k2] * Pk[k2 * 4 + j];
    }
    qo[j] = f2bf(aq);
    ko[j] = f2bf(ak);
  }
  size_t base = ((size_t)h * 2048 + s) * 64 + dvb;
  *(short4v*)(qb + base) = qo;
  *(short4v*)(kb + base) = ko;
#pragma unroll
  for (int j = 0; j < 4; j++)
    vt[((size_t)h * 64 + dvb + j) * 2048 + s] = f2bf(vv[j]);
}

// ---------------- flash attention ----------------
// qb,kb: [20][2048][64], vt: [20][64][2048], attn_out bf16 [2048][1280]
__global__ __launch_bounds__(256) void attn_kernel(
    const short* __restrict__ qb, const short* __restrict__ kb,
    const short* __restrict__ vt, short* __restrict__ attn_out) {
  const int S = 2048, HD = 64;
  int h = blockIdx.x;
  int qblk = blockIdx.y;
  int tid = threadIdx.x;
  int w = tid >> 6, l = tid & 63;
  int lr = l & 15, lg = l >> 4;
  int q0 = qblk * 64 + w * 16;

  __shared__ __align__(16) short pbuf_all[4][16][72];  // padded rows: 144B = 9*16B
  short(*pbuf)[72] = pbuf_all[w];

  // Q fragment (B operand of S^T mfma): lane holds Q[q0+lr][lg*8 + j] per 32-d half
  const short* qptr = qb + ((size_t)h * S + q0 + lr) * HD;
  short8 qf0 = *(const short8*)(qptr + lg * 8);
  short8 qf1 = *(const short8*)(qptr + 32 + lg * 8);

  float m = -1e30f, lsum = 0.f;
  f32x4 oacc[4] = {};  // dv blocks of 16, D rows = q = lg*4+i

  for (int kt = 0; kt < S; kt += 64) {
    float sv[16];
#pragma unroll
    for (int kk = 0; kk < 4; kk++) {
      const short* kptr = kb + ((size_t)h * S + kt + kk * 16 + lr) * HD;
      short8 kf0 = *(const short8*)(kptr + lg * 8);
      short8 kf1 = *(const short8*)(kptr + 32 + lg * 8);
      f32x4 st = {};
      st = mfma16(kf0, qf0, st);
      st = mfma16(kf1, qf1, st);
#pragma unroll
      for (int i = 0; i < 4; i++) sv[kk * 4 + i] = st[i] * 0.125f;
    }
    // row max over tile (each lane holds 16 scores of q-row lr)
    float tm = sv[0];
#pragma unroll
    for (int i = 1; i < 16; i++) tm = fmaxf(tm, sv[i]);
    tm = fmaxf(tm, __shfl_xor(tm, 16));
    tm = fmaxf(tm, __shfl_xor(tm, 32));
    float mnew = fmaxf(m, tm);
    float fac = __expf(m - mnew);
    float psum = 0.f;
#pragma unroll
    for (int i = 0; i < 16; i++) {
      float p = __expf(sv[i] - mnew);
      sv[i] = p;
      psum += p;
    }
    psum += __shfl_xor(psum, 16);
    psum += __shfl_xor(psum, 32);
    lsum = lsum * fac + psum;
    m = mnew;
    // rescale O (rows q = lg*4+i) by fac(q) fetched from lane q
#pragma unroll
    for (int i = 0; i < 4; i++) {
      float fi = __shfl(fac, lg * 4 + i);
#pragma unroll
      for (int nb = 0; nb < 4; nb++) oacc[nb][i] *= fi;
    }
    // P -> LDS (bf16), layout pbuf[q][key]
#pragma unroll
    for (int kk = 0; kk < 4; kk++)
#pragma unroll
      for (int i = 0; i < 4; i++)
        pbuf[lr][kk * 16 + lg * 4 + i] = f2bf(sv[kk * 4 + i]);
    asm volatile("s_waitcnt lgkmcnt(0)" ::: "memory");
    __builtin_amdgcn_sched_barrier(0);
    // PV: O[q][dv] += P[q][key] V[key][dv]
#pragma unroll
    for (int kh = 0; kh < 2; kh++) {
      short8 pf = *(const short8*)(&pbuf[lr][kh * 32 + lg * 8]);
#pragma unroll
      for (int nb = 0; nb < 4; nb++) {
        const short* vptr =
            vt + ((size_t)h * HD + nb * 16 + lr) * S + kt + kh * 32 + lg * 8;
        short8 vf = *(const short8*)(vptr);
        oacc[nb] = mfma16(pf, vf, oacc[nb]);
      }
    }
    asm volatile("s_waitcnt lgkmcnt(0)" ::: "memory");
    __builtin_amdgcn_sched_barrier(0);
  }
  // normalize + store: lane holds O[q=lg*4+i][dv=nb*16+lr]
#pragma unroll
  for (int i = 0; i < 4; i++) {
    float li = __shfl(lsum, lg * 4 + i);
    float inv = 1.0f / li;
    int row = q0 + lg * 4 + i;
#pragma unroll
    for (int nb = 0; nb < 4; nb++)
      attn_out[(size_t)row * 1280 + h * 64 + nb * 16 + lr] = f2bf(oacc[nb][i] * inv);
  }
}

// ---------------- launch ----------------

extern "C" void kernel_launch(void* const* d_in, const int* in_sizes, int n_in,
                              void* d_out, int out_size, void* d_ws, size_t ws_size,
                              hipStream_t stream) {
  const float* hs = (const float*)d_in[0];
  const float* p_out = (const float*)d_in[1];
  const float* p_inv = (const float*)d_in[2];
  const float* Wq = (const float*)d_in[3];
  const float* Wk = (const float*)d_in[4];
  const float* Wv = (const float*)d_in[5];
  const float* Wo = (const float*)d_in[6];
  const float* bo = (const float*)d_in[7];
  float* out = (float*)d_out;
  char* ws = (char*)d_ws;

  // workspace layout (all offsets 256B-aligned)
  short* hs_bf = (short*)(ws + 0);              // 2048*1280*2   = 5,242,880
  short* wqkv_t = (short*)(ws + 5242880);       // 3840*1280*2   = 9,830,400
  short* wo_t = (short*)(ws + 15073280);        // 1280*1280*2   = 3,276,800
  float* qkv = (float*)(ws + 18350080);         // 2048*3840*4   = 31,457,280
  short* q_bf = (short*)(ws + 49807360);        // 20*2048*64*2  = 5,242,880
  short* k_bf = (short*)(ws + 55050240);        // 5,242,880
  short* v_t = (short*)(ws + 60293120);         // 5,242,880  (ends 65,536,000)
  short* attn_bf = (short*)(ws + 18350080);     // reuse qkv region after cape_split

  const int n_hs = 2048 * 1280;
  cvt_bf16_kernel<<<(n_hs + 255) / 256, 256, 0, stream>>>(hs, hs_bf, n_hs);

  dim3 tb(32, 8);
  transpose_cvt_kernel<<<dim3(40, 40), tb, 0, stream>>>(Wq, wqkv_t, 1280, 1280);
  transpose_cvt_kernel<<<dim3(40, 40), tb, 0, stream>>>(Wk, wqkv_t + (size_t)1280 * 1280, 1280, 1280);
  transpose_cvt_kernel<<<dim3(40, 40), tb, 0, stream>>>(Wv, wqkv_t + (size_t)2560 * 1280, 1280, 1280);
  transpose_cvt_kernel<<<dim3(40, 40), tb, 0, stream>>>(Wo, wo_t, 1280, 1280);

  // QKV: [2048][1280] @ [1280][3840] -> [2048][3840] f32
  gemm_bt_kernel<0><<<dim3(60, 32), 256, 0, stream>>>(
      hs_bf, wqkv_t, 2048, 3840, 1280, qkv, nullptr, nullptr, nullptr);

  cape_split_kernel<<<2560, 256, 0, stream>>>(qkv, p_out, p_inv, q_bf, k_bf, v_t);

  attn_kernel<<<dim3(20, 32), 256, 0, stream>>>(q_bf, k_bf, v_t, attn_bf);

  // out = attn @ Wo + bo + residual
  gemm_bt_kernel<1><<<dim3(20, 32), 256, 0, stream>>>(
      attn_bf, wo_t, 2048, 1280, 1280, nullptr, bo, hs, out);
}